// Round 1
// baseline (313.577 us; speedup 1.0000x reference)
//
#include <hip/hip_runtime.h>
#include <hip/hip_bf16.h>

// Problem constants
#define NB 32     // batch
#define NL 2048   // seq len
#define ND 1024   // DQ = DK = NH*DH
#define NHH 16    // heads
#define NDH 64    // head dim

typedef __bf16 bf16;
typedef __attribute__((ext_vector_type(8))) __bf16 bf16x8;
typedef __attribute__((ext_vector_type(4))) float f32x4;

__device__ __forceinline__ float dot4(float4 a, float4 b) {
  return a.x * b.x + a.y * b.y + a.z * b.z + a.w * b.w;
}

// ---------------------------------------------------------------------------
// K1: qs[b][o] = q[b] . Wq[o] + bq[o]      (o = n*64+d), grid=1024, block=256
// Each wave: holds Wq row slice (16 f32/lane), loops 8 batches, shuffle-reduce.
// ---------------------------------------------------------------------------
__global__ __launch_bounds__(256) void qs_kernel(
    const float* __restrict__ q, const float* __restrict__ Wq,
    const float* __restrict__ bq, float* __restrict__ qs) {
  int o = blockIdx.x;
  int lane = threadIdx.x & 63;
  int wv = threadIdx.x >> 6;
  const float4* wrow = reinterpret_cast<const float4*>(Wq + (size_t)o * ND) + lane * 4;
  float4 w0 = wrow[0], w1 = wrow[1], w2 = wrow[2], w3 = wrow[3];
#pragma unroll
  for (int bb = 0; bb < 8; ++bb) {
    int b = wv * 8 + bb;
    const float4* qr = reinterpret_cast<const float4*>(q + (size_t)b * ND) + lane * 4;
    float s = dot4(qr[0], w0) + dot4(qr[1], w1) + dot4(qr[2], w2) + dot4(qr[3], w3);
#pragma unroll
    for (int off = 32; off > 0; off >>= 1) s += __shfl_down(s, off, 64);
    if (lane == 0) qs[(size_t)b * ND + o] = s + bq[o];
  }
}

// ---------------------------------------------------------------------------
// K2: qt[b][n][i] = sum_d Wk[n*64+d][i] * qs[b][n*64+d]   grid=64 (n,ichunk)
// ---------------------------------------------------------------------------
__global__ __launch_bounds__(256) void qt_kernel(
    const float* __restrict__ Wk, const float* __restrict__ qs,
    float* __restrict__ qt) {
  int n = blockIdx.x >> 2;
  int ic = blockIdx.x & 3;
  int i = ic * 256 + threadIdx.x;
  __shared__ float s_qs[32][64];
  for (int t = threadIdx.x; t < 2048; t += 256) {
    int b = t >> 6, d = t & 63;
    s_qs[b][d] = qs[(size_t)b * ND + n * NDH + d];
  }
  __syncthreads();
  float acc[32];
#pragma unroll
  for (int b = 0; b < 32; ++b) acc[b] = 0.f;
  for (int d = 0; d < 64; ++d) {
    float w = Wk[((size_t)(n * NDH + d)) * ND + i];
#pragma unroll
    for (int b = 0; b < 32; ++b) acc[b] += w * s_qs[b][d];
  }
#pragma unroll
  for (int b = 0; b < 32; ++b)
    qt[((size_t)(b * NHH + n)) * ND + i] = acc[b];
}

// ---------------------------------------------------------------------------
// K2b: qb[b*16+n] = qs[b][n*64+:] . bk[n*64+:]    grid=2, block=256
// ---------------------------------------------------------------------------
__global__ __launch_bounds__(256) void qb_kernel(
    const float* __restrict__ qs, const float* __restrict__ bk,
    float* __restrict__ qb) {
  int t = blockIdx.x * 256 + threadIdx.x;
  if (t >= 512) return;
  int b = t >> 4, n = t & 15;
  float s = 0.f;
  for (int d = 0; d < 64; ++d)
    s += qs[(size_t)b * ND + n * NDH + d] * bk[n * NDH + d];
  qb[t] = s;
}

// ---------------------------------------------------------------------------
// K3: logits[n*32+b][l] = (qt[b][n] . k[b][l] + qb[b][n]) / 8   via bf16 MFMA
// grid = 32 b x 32 ltiles(64 l), block = 256 (4 waves, one 16-l subtile each)
// LDS: sA = qt[b] bf16 [16][1024] (32KB), sB = k chunk bf16 [64][256] (32KB)
// Both XOR-swizzled byte ^= ((row&7)<<4) to kill stride-2048B/512B conflicts.
// ---------------------------------------------------------------------------
__global__ __launch_bounds__(256) void logits_kernel(
    const float* __restrict__ kin, const float* __restrict__ qt,
    const float* __restrict__ qb, float* __restrict__ attn) {
  int b = blockIdx.x >> 5;
  int lt = blockIdx.x & 31;
  int l0 = lt * 64;
  int tid = threadIdx.x;
  int lane = tid & 63, wv = tid >> 6;

  __shared__ __align__(16) char sA[16 * 1024 * 2];
  __shared__ __align__(16) char sB[64 * 256 * 2];

  {  // stage qt[b] -> sA (bf16, swizzled). thread t: row n=t>>4, cols (t&15)*64..+63
    int n = tid >> 4, c0 = (tid & 15) * 64;
    const float4* src =
        reinterpret_cast<const float4*>(qt + ((size_t)(b * NHH + n)) * ND + c0);
#pragma unroll
    for (int m = 0; m < 8; ++m) {
      float4 f0 = src[2 * m], f1 = src[2 * m + 1];
      bf16x8 v;
      v[0] = (bf16)f0.x; v[1] = (bf16)f0.y; v[2] = (bf16)f0.z; v[3] = (bf16)f0.w;
      v[4] = (bf16)f1.x; v[5] = (bf16)f1.y; v[6] = (bf16)f1.z; v[7] = (bf16)f1.w;
      int byte = ((n * 1024 + c0 + m * 8) * 2) ^ ((n & 7) << 4);
      *reinterpret_cast<bf16x8*>(sA + byte) = v;
    }
  }

  f32x4 acc = {0.f, 0.f, 0.f, 0.f};
  int rA = lane & 15;   // A row (n) / B col (l within subtile)
  int kg = lane >> 4;   // K group: fragment k = kg*8 + j (contiguous 8)

  for (int kc = 0; kc < ND; kc += 256) {
    __syncthreads();  // previous chunk's MFMAs done (and sA staged, 1st iter)
    {  // stage k[b][l0..l0+63][kc..kc+255] -> sB. thread: row l=t>>2, 64 cols
      int l = tid >> 2, cg = tid & 3;
      const float4* src = reinterpret_cast<const float4*>(
          kin + ((size_t)(b * NL + l0 + l)) * ND + kc + cg * 64);
#pragma unroll
      for (int m = 0; m < 8; ++m) {
        float4 f0 = src[2 * m], f1 = src[2 * m + 1];
        bf16x8 v;
        v[0] = (bf16)f0.x; v[1] = (bf16)f0.y; v[2] = (bf16)f0.z; v[3] = (bf16)f0.w;
        v[4] = (bf16)f1.x; v[5] = (bf16)f1.y; v[6] = (bf16)f1.z; v[7] = (bf16)f1.w;
        int byte = ((l * 256 + cg * 64 + m * 8) * 2) ^ ((l & 7) << 4);
        *reinterpret_cast<bf16x8*>(sB + byte) = v;
      }
    }
    __syncthreads();
    int lB = wv * 16 + rA;
#pragma unroll
    for (int kk = 0; kk < 8; ++kk) {
      int byteA = ((rA * 1024 + kc + kk * 32 + kg * 8) * 2) ^ ((rA & 7) << 4);
      bf16x8 a = *reinterpret_cast<const bf16x8*>(sA + byteA);
      int byteB = ((lB * 256 + kk * 32 + kg * 8) * 2) ^ ((lB & 7) << 4);
      bf16x8 bf = *reinterpret_cast<const bf16x8*>(sB + byteB);
      acc = __builtin_amdgcn_mfma_f32_16x16x32_bf16(a, bf, acc, 0, 0, 0);
    }
  }

  // C/D layout (m89/m91): col = lane&15, row = (lane>>4)*4 + j
  int c = lane & 15;
  int rb = (lane >> 4) * 4;
#pragma unroll
  for (int j = 0; j < 4; ++j) {
    int r = rb + j;  // head n
    float val = (acc[j] + qb[b * NHH + r]) * 0.125f;
    attn[((size_t)(r * NB + b)) * NL + l0 + wv * 16 + c] = val;
  }
}

// ---------------------------------------------------------------------------
// K4: in-place softmax over rows of 2048. grid=512, block=256 (8 elems/thread)
// ---------------------------------------------------------------------------
__global__ __launch_bounds__(256) void softmax_kernel(float* __restrict__ attn) {
  int row = blockIdx.x;
  float* p = attn + (size_t)row * NL;
  int tid = threadIdx.x;
  int lane = tid & 63, wv = tid >> 6;
  float v[8];
  float m = -1e30f;
#pragma unroll
  for (int j = 0; j < 8; ++j) {
    v[j] = p[tid + j * 256];
    m = fmaxf(m, v[j]);
  }
#pragma unroll
  for (int off = 32; off > 0; off >>= 1) m = fmaxf(m, __shfl_down(m, off, 64));
  __shared__ float sm[4], ss[4];
  if (lane == 0) sm[wv] = m;
  __syncthreads();
  float M = fmaxf(fmaxf(sm[0], sm[1]), fmaxf(sm[2], sm[3]));
  float s = 0.f;
#pragma unroll
  for (int j = 0; j < 8; ++j) {
    v[j] = __expf(v[j] - M);
    s += v[j];
  }
#pragma unroll
  for (int off = 32; off > 0; off >>= 1) s += __shfl_down(s, off, 64);
  if (lane == 0) ss[wv] = s;
  __syncthreads();
  float inv = 1.f / (ss[0] + ss[1] + ss[2] + ss[3]);
#pragma unroll
  for (int j = 0; j < 8; ++j) p[tid + j * 256] = v[j] * inv;
}

// ---------------------------------------------------------------------------
// K5: ctx[b][n][i] = sum_l attn[n*32+b][l] * k[b][l][i]
// grid = 32 b x 8 ichunks(128 i), block=256: half-threads do l<1024, half rest.
// attn factors are thread-uniform -> scalar loads; k loads coalesced dwords.
// ---------------------------------------------------------------------------
__global__ __launch_bounds__(256) void ctx_kernel(
    const float* __restrict__ kin, const float* __restrict__ attn,
    float* __restrict__ ctx) {
  int b = blockIdx.x >> 3;
  int ic = blockIdx.x & 7;
  int tid = threadIdx.x;
  int i = ic * 128 + (tid & 127);
  int lh = tid >> 7;
  const float* kb = kin + ((size_t)b * NL) * ND + i;
  float acc[16];
#pragma unroll
  for (int n = 0; n < 16; ++n) acc[n] = 0.f;
  int lbeg = lh * 1024, lend = lbeg + 1024;
#pragma unroll 4
  for (int l = lbeg; l < lend; ++l) {
    float kv = kb[(size_t)l * ND];
#pragma unroll
    for (int n = 0; n < 16; ++n)
      acc[n] += attn[((size_t)(n * NB + b)) * NL + l] * kv;
  }
  __shared__ float part[128][17];
  if (lh == 1) {
#pragma unroll
    for (int n = 0; n < 16; ++n) part[tid & 127][n] = acc[n];
  }
  __syncthreads();
  if (lh == 0) {
#pragma unroll
    for (int n = 0; n < 16; ++n)
      ctx[((size_t)(b * NHH + n)) * ND + i] = acc[n] + part[tid][n];
  }
}

// ---------------------------------------------------------------------------
// K6: out[b][o] = Wv[o] . ctx[b][o>>6] + bv[o]     grid=1024, block=256
// ---------------------------------------------------------------------------
__global__ __launch_bounds__(256) void out_kernel(
    const float* __restrict__ Wv, const float* __restrict__ bv,
    const float* __restrict__ ctx, float* __restrict__ out) {
  int o = blockIdx.x;
  int n = o >> 6;
  int lane = threadIdx.x & 63;
  int wv = threadIdx.x >> 6;
  const float4* wrow = reinterpret_cast<const float4*>(Wv + (size_t)o * ND) + lane * 4;
  float4 w0 = wrow[0], w1 = wrow[1], w2 = wrow[2], w3 = wrow[3];
#pragma unroll
  for (int bb = 0; bb < 8; ++bb) {
    int b = wv * 8 + bb;
    const float4* cr =
        reinterpret_cast<const float4*>(ctx + ((size_t)(b * NHH + n)) * ND) + lane * 4;
    float s = dot4(cr[0], w0) + dot4(cr[1], w1) + dot4(cr[2], w2) + dot4(cr[3], w3);
#pragma unroll
    for (int off = 32; off > 0; off >>= 1) s += __shfl_down(s, off, 64);
    if (lane == 0) out[(size_t)b * ND + o] = s + bv[o];
  }
}

// ---------------------------------------------------------------------------
extern "C" void kernel_launch(void* const* d_in, const int* in_sizes, int n_in,
                              void* d_out, int out_size, void* d_ws, size_t ws_size,
                              hipStream_t stream) {
  const float* q  = (const float*)d_in[0];
  const float* k  = (const float*)d_in[1];
  const float* Wq = (const float*)d_in[2];
  const float* bq = (const float*)d_in[3];
  const float* Wk = (const float*)d_in[4];
  const float* bk = (const float*)d_in[5];
  const float* Wv = (const float*)d_in[6];
  const float* bv = (const float*)d_in[7];

  float* out  = (float*)d_out;         // [32][1024]
  float* attn = out + NB * ND;         // [512][2048]  (n-major: (n*32+b)*2048+l)

  // workspace layout (floats): qs 32768 | qt 524288 | qb 512 | ctx 524288
  // total ~4.2 MiB
  float* ws  = (float*)d_ws;
  float* qs  = ws;
  float* qt  = ws + 32768;
  float* qb  = ws + 32768 + 524288;
  float* ctx = ws + 32768 + 524288 + 512;

  qs_kernel<<<1024, 256, 0, stream>>>(q, Wq, bq, qs);
  qt_kernel<<<64, 256, 0, stream>>>(Wk, qs, qt);
  qb_kernel<<<2, 256, 0, stream>>>(qs, bk, qb);
  logits_kernel<<<1024, 256, 0, stream>>>(k, qt, qb, attn);
  softmax_kernel<<<512, 256, 0, stream>>>(attn);
  ctx_kernel<<<256, 256, 0, stream>>>(k, attn, ctx);
  out_kernel<<<1024, 256, 0, stream>>>(Wv, bv, ctx, out);
}

// Round 2
// 166.519 us; speedup vs baseline: 1.8831x; 1.8831x over previous
//
#include <hip/hip_runtime.h>
#include <hip/hip_bf16.h>

// Problem constants
#define NB 32     // batch
#define NL 2048   // seq len
#define ND 1024   // DQ = DK = NH*DH
#define NHH 16    // heads
#define NDH 64    // head dim

typedef __bf16 bf16;
typedef __attribute__((ext_vector_type(8))) __bf16 bf16x8;
typedef __attribute__((ext_vector_type(4))) float f32x4;

__device__ __forceinline__ float dot4(float4 a, float4 b) {
  return a.x * b.x + a.y * b.y + a.z * b.z + a.w * b.w;
}

// ---------------------------------------------------------------------------
// K1: qs[b][o] = q[b] . Wq[o] + bq[o]      (o = n*64+d), grid=1024, block=256
// ---------------------------------------------------------------------------
__global__ __launch_bounds__(256) void qs_kernel(
    const float* __restrict__ q, const float* __restrict__ Wq,
    const float* __restrict__ bq, float* __restrict__ qs) {
  int o = blockIdx.x;
  int lane = threadIdx.x & 63;
  int wv = threadIdx.x >> 6;
  const float4* wrow = reinterpret_cast<const float4*>(Wq + (size_t)o * ND) + lane * 4;
  float4 w0 = wrow[0], w1 = wrow[1], w2 = wrow[2], w3 = wrow[3];
#pragma unroll
  for (int bb = 0; bb < 8; ++bb) {
    int b = wv * 8 + bb;
    const float4* qr = reinterpret_cast<const float4*>(q + (size_t)b * ND) + lane * 4;
    float s = dot4(qr[0], w0) + dot4(qr[1], w1) + dot4(qr[2], w2) + dot4(qr[3], w3);
#pragma unroll
    for (int off = 32; off > 0; off >>= 1) s += __shfl_down(s, off, 64);
    if (lane == 0) qs[(size_t)b * ND + o] = s + bq[o];
  }
}

// ---------------------------------------------------------------------------
// K2: qt[b][n][i] = sum_d Wk[n*64+d][i] * qs[b][n*64+d]   grid=64 (n,ichunk)
// ---------------------------------------------------------------------------
__global__ __launch_bounds__(256) void qt_kernel(
    const float* __restrict__ Wk, const float* __restrict__ qs,
    float* __restrict__ qt) {
  int n = blockIdx.x >> 2;
  int ic = blockIdx.x & 3;
  int i = ic * 256 + threadIdx.x;
  __shared__ float s_qs[32][64];
  for (int t = threadIdx.x; t < 2048; t += 256) {
    int b = t >> 6, d = t & 63;
    s_qs[b][d] = qs[(size_t)b * ND + n * NDH + d];
  }
  __syncthreads();
  float acc[32];
#pragma unroll
  for (int b = 0; b < 32; ++b) acc[b] = 0.f;
  for (int d = 0; d < 64; ++d) {
    float w = Wk[((size_t)(n * NDH + d)) * ND + i];
#pragma unroll
    for (int b = 0; b < 32; ++b) acc[b] += w * s_qs[b][d];
  }
#pragma unroll
  for (int b = 0; b < 32; ++b)
    qt[((size_t)(b * NHH + n)) * ND + i] = acc[b];
}

// ---------------------------------------------------------------------------
// K2b: qb[b*16+n] = qs[b][n*64+:] . bk[n*64+:]    grid=2, block=256
// ---------------------------------------------------------------------------
__global__ __launch_bounds__(256) void qb_kernel(
    const float* __restrict__ qs, const float* __restrict__ bk,
    float* __restrict__ qb) {
  int t = blockIdx.x * 256 + threadIdx.x;
  if (t >= 512) return;
  int b = t >> 4, n = t & 15;
  float s = 0.f;
  for (int d = 0; d < 64; ++d)
    s += qs[(size_t)b * ND + n * NDH + d] * bk[n * NDH + d];
  qb[t] = s;
}

// ---------------------------------------------------------------------------
// K3: logits[n*32+b][l] = (qt[b][n] . k[b][l] + qb[b][n]) / 8   via bf16 MFMA
// ---------------------------------------------------------------------------
__global__ __launch_bounds__(256) void logits_kernel(
    const float* __restrict__ kin, const float* __restrict__ qt,
    const float* __restrict__ qb, float* __restrict__ attn) {
  int b = blockIdx.x >> 5;
  int lt = blockIdx.x & 31;
  int l0 = lt * 64;
  int tid = threadIdx.x;
  int lane = tid & 63, wv = tid >> 6;

  __shared__ __align__(16) char sA[16 * 1024 * 2];
  __shared__ __align__(16) char sB[64 * 256 * 2];

  {  // stage qt[b] -> sA (bf16, swizzled)
    int n = tid >> 4, c0 = (tid & 15) * 64;
    const float4* src =
        reinterpret_cast<const float4*>(qt + ((size_t)(b * NHH + n)) * ND + c0);
#pragma unroll
    for (int m = 0; m < 8; ++m) {
      float4 f0 = src[2 * m], f1 = src[2 * m + 1];
      bf16x8 v;
      v[0] = (bf16)f0.x; v[1] = (bf16)f0.y; v[2] = (bf16)f0.z; v[3] = (bf16)f0.w;
      v[4] = (bf16)f1.x; v[5] = (bf16)f1.y; v[6] = (bf16)f1.z; v[7] = (bf16)f1.w;
      int byte = ((n * 1024 + c0 + m * 8) * 2) ^ ((n & 7) << 4);
      *reinterpret_cast<bf16x8*>(sA + byte) = v;
    }
  }

  f32x4 acc = {0.f, 0.f, 0.f, 0.f};
  int rA = lane & 15;
  int kg = lane >> 4;

  for (int kc = 0; kc < ND; kc += 256) {
    __syncthreads();
    {  // stage k[b][l0..l0+63][kc..kc+255] -> sB
      int l = tid >> 2, cg = tid & 3;
      const float4* src = reinterpret_cast<const float4*>(
          kin + ((size_t)(b * NL + l0 + l)) * ND + kc + cg * 64);
#pragma unroll
      for (int m = 0; m < 8; ++m) {
        float4 f0 = src[2 * m], f1 = src[2 * m + 1];
        bf16x8 v;
        v[0] = (bf16)f0.x; v[1] = (bf16)f0.y; v[2] = (bf16)f0.z; v[3] = (bf16)f0.w;
        v[4] = (bf16)f1.x; v[5] = (bf16)f1.y; v[6] = (bf16)f1.z; v[7] = (bf16)f1.w;
        int byte = ((l * 256 + cg * 64 + m * 8) * 2) ^ ((l & 7) << 4);
        *reinterpret_cast<bf16x8*>(sB + byte) = v;
      }
    }
    __syncthreads();
    int lB = wv * 16 + rA;
#pragma unroll
    for (int kk = 0; kk < 8; ++kk) {
      int byteA = ((rA * 1024 + kc + kk * 32 + kg * 8) * 2) ^ ((rA & 7) << 4);
      bf16x8 a = *reinterpret_cast<const bf16x8*>(sA + byteA);
      int byteB = ((lB * 256 + kk * 32 + kg * 8) * 2) ^ ((lB & 7) << 4);
      bf16x8 bf = *reinterpret_cast<const bf16x8*>(sB + byteB);
      acc = __builtin_amdgcn_mfma_f32_16x16x32_bf16(a, bf, acc, 0, 0, 0);
    }
  }

  int c = lane & 15;
  int rb = (lane >> 4) * 4;
#pragma unroll
  for (int j = 0; j < 4; ++j) {
    int r = rb + j;  // head n
    float val = (acc[j] + qb[b * NHH + r]) * 0.125f;
    attn[((size_t)(r * NB + b)) * NL + l0 + wv * 16 + c] = val;
  }
}

// ---------------------------------------------------------------------------
// K4: in-place softmax over rows of 2048. grid=512, block=256
// ---------------------------------------------------------------------------
__global__ __launch_bounds__(256) void softmax_kernel(float* __restrict__ attn) {
  int row = blockIdx.x;
  float* p = attn + (size_t)row * NL;
  int tid = threadIdx.x;
  int lane = tid & 63, wv = tid >> 6;
  float v[8];
  float m = -1e30f;
#pragma unroll
  for (int j = 0; j < 8; ++j) {
    v[j] = p[tid + j * 256];
    m = fmaxf(m, v[j]);
  }
#pragma unroll
  for (int off = 32; off > 0; off >>= 1) m = fmaxf(m, __shfl_down(m, off, 64));
  __shared__ float sm[4], ss[4];
  if (lane == 0) sm[wv] = m;
  __syncthreads();
  float M = fmaxf(fmaxf(sm[0], sm[1]), fmaxf(sm[2], sm[3]));
  float s = 0.f;
#pragma unroll
  for (int j = 0; j < 8; ++j) {
    v[j] = __expf(v[j] - M);
    s += v[j];
  }
#pragma unroll
  for (int off = 32; off > 0; off >>= 1) s += __shfl_down(s, off, 64);
  if (lane == 0) ss[wv] = s;
  __syncthreads();
  float inv = 1.f / (ss[0] + ss[1] + ss[2] + ss[3]);
#pragma unroll
  for (int j = 0; j < 8; ++j) p[tid + j * 256] = v[j] * inv;
}

// ---------------------------------------------------------------------------
// K5: ctx[b][n][i] = sum_l attn[n*32+b][l] * k[b][l][i]
// grid = 32 b x 4 ig(256 i) x 8 ls(256 l) = 1024 blocks, 256 threads.
// Thread: 4 consecutive i (one float4 k-load per l), 16 n accumulators.
// attn slice staged in LDS [l][n] (80B rows, wave-uniform broadcast reads).
// Wave partials combined in LDS, block partial atomicAdd'ed to ctx.
// ---------------------------------------------------------------------------
__global__ __launch_bounds__(256, 4) void ctx_kernel(
    const float* __restrict__ kin, const float* __restrict__ attn,
    float* __restrict__ ctx) {
  int bx = blockIdx.x;
  int b  = bx >> 5;          // 0..31
  int ig = (bx >> 3) & 3;    // 0..3
  int ls = bx & 7;           // 0..7
  int tid = threadIdx.x, lane = tid & 63, wv = tid >> 6;

  __shared__ __align__(16) float sA[256][20];  // attn [l][n], rows 80B
  __shared__ __align__(16) float sC[16][256];  // combine buffer

  // stage attn slice: n = idx>>8, l = idx&255 (coalesced over l)
  for (int idx = tid; idx < 4096; idx += 256) {
    int n = idx >> 8, ll = idx & 255;
    sA[ll][n] = attn[((size_t)(n * NB + b)) * NL + ls * 256 + ll];
  }
  __syncthreads();

  f32x4 acc[16];
#pragma unroll
  for (int n = 0; n < 16; ++n) acc[n] = (f32x4){0.f, 0.f, 0.f, 0.f};

  const float* kp =
      kin + ((size_t)(b * NL + ls * 256 + wv * 64)) * ND + ig * 256 + lane * 4;
  int row0 = wv * 64;
#pragma unroll 2
  for (int l = 0; l < 64; ++l) {
    f32x4 kv = *reinterpret_cast<const f32x4*>(kp + (size_t)l * ND);
    const float* ar = sA[row0 + l];
    f32x4 aa[4];
    aa[0] = *reinterpret_cast<const f32x4*>(ar);
    aa[1] = *reinterpret_cast<const f32x4*>(ar + 4);
    aa[2] = *reinterpret_cast<const f32x4*>(ar + 8);
    aa[3] = *reinterpret_cast<const f32x4*>(ar + 12);
#pragma unroll
    for (int n = 0; n < 16; ++n) {
#pragma unroll
      for (int c = 0; c < 4; ++c)
        acc[n][c] += aa[n >> 2][n & 3] * kv[c];
    }
  }

  // combine 4 waves' partials in LDS (sequential adds)
  if (wv == 0) {
#pragma unroll
    for (int n = 0; n < 16; ++n)
      *reinterpret_cast<f32x4*>(&sC[n][lane * 4]) = acc[n];
  }
  __syncthreads();
#pragma unroll
  for (int w = 1; w < 4; ++w) {
    if (wv == w) {
#pragma unroll
      for (int n = 0; n < 16; ++n) {
        f32x4 cur = *reinterpret_cast<f32x4*>(&sC[n][lane * 4]);
        cur += acc[n];
        *reinterpret_cast<f32x4*>(&sC[n][lane * 4]) = cur;
      }
    }
    __syncthreads();
  }

  // atomic-add block partial into ctx
  for (int idx = tid; idx < 4096; idx += 256) {
    int n = idx >> 8, i = idx & 255;
    atomicAdd(&ctx[((size_t)(b * NHH + n)) * ND + ig * 256 + i], sC[n][i]);
  }
}

// ---------------------------------------------------------------------------
// K6: out[b][o] = Wv[o] . ctx[b][o>>6] + bv[o]     grid=1024, block=256
// ---------------------------------------------------------------------------
__global__ __launch_bounds__(256) void out_kernel(
    const float* __restrict__ Wv, const float* __restrict__ bv,
    const float* __restrict__ ctx, float* __restrict__ out) {
  int o = blockIdx.x;
  int n = o >> 6;
  int lane = threadIdx.x & 63;
  int wv = threadIdx.x >> 6;
  const float4* wrow = reinterpret_cast<const float4*>(Wv + (size_t)o * ND) + lane * 4;
  float4 w0 = wrow[0], w1 = wrow[1], w2 = wrow[2], w3 = wrow[3];
#pragma unroll
  for (int bb = 0; bb < 8; ++bb) {
    int b = wv * 8 + bb;
    const float4* cr =
        reinterpret_cast<const float4*>(ctx + ((size_t)(b * NHH + n)) * ND) + lane * 4;
    float s = dot4(cr[0], w0) + dot4(cr[1], w1) + dot4(cr[2], w2) + dot4(cr[3], w3);
#pragma unroll
    for (int off = 32; off > 0; off >>= 1) s += __shfl_down(s, off, 64);
    if (lane == 0) out[(size_t)b * ND + o] = s + bv[o];
  }
}

// ---------------------------------------------------------------------------
extern "C" void kernel_launch(void* const* d_in, const int* in_sizes, int n_in,
                              void* d_out, int out_size, void* d_ws, size_t ws_size,
                              hipStream_t stream) {
  const float* q  = (const float*)d_in[0];
  const float* k  = (const float*)d_in[1];
  const float* Wq = (const float*)d_in[2];
  const float* bq = (const float*)d_in[3];
  const float* Wk = (const float*)d_in[4];
  const float* bk = (const float*)d_in[5];
  const float* Wv = (const float*)d_in[6];
  const float* bv = (const float*)d_in[7];

  float* out  = (float*)d_out;         // [32][1024]
  float* attn = out + NB * ND;         // [512][2048]  (n-major)

  // workspace: qs 32768 | qt 524288 | qb 512 | ctx 524288 floats (~4.2 MiB)
  float* ws  = (float*)d_ws;
  float* qs  = ws;
  float* qt  = ws + 32768;
  float* qb  = ws + 32768 + 524288;
  float* ctx = ws + 32768 + 524288 + 512;

  hipMemsetAsync(ctx, 0, (size_t)NB * NHH * ND * sizeof(float), stream);

  qs_kernel<<<1024, 256, 0, stream>>>(q, Wq, bq, qs);
  qt_kernel<<<64, 256, 0, stream>>>(Wk, qs, qt);
  qb_kernel<<<2, 256, 0, stream>>>(qs, bk, qb);
  logits_kernel<<<1024, 256, 0, stream>>>(k, qt, qb, attn);
  softmax_kernel<<<512, 256, 0, stream>>>(attn);
  ctx_kernel<<<1024, 256, 0, stream>>>(k, attn, ctx);
  out_kernel<<<1024, 256, 0, stream>>>(Wv, bv, ctx, out);
}

// Round 3
// 164.573 us; speedup vs baseline: 1.9054x; 1.0118x over previous
//
#include <hip/hip_runtime.h>
#include <hip/hip_bf16.h>

// Problem constants
#define NB 32     // batch
#define NL 2048   // seq len
#define ND 1024   // DQ = DK = NH*DH
#define NHH 16    // heads
#define NDH 64    // head dim

typedef __bf16 bf16;
typedef __attribute__((ext_vector_type(8))) __bf16 bf16x8;
typedef __attribute__((ext_vector_type(4))) float f32x4;

__device__ __forceinline__ float dot4(float4 a, float4 b) {
  return a.x * b.x + a.y * b.y + a.z * b.z + a.w * b.w;
}

// ---------------------------------------------------------------------------
// K1: qs[b][o] = q[b] . Wq[o] + bq[o]      (o = n*64+d), grid=1024, block=256
// ---------------------------------------------------------------------------
__global__ __launch_bounds__(256) void qs_kernel(
    const float* __restrict__ q, const float* __restrict__ Wq,
    const float* __restrict__ bq, float* __restrict__ qs) {
  int o = blockIdx.x;
  int lane = threadIdx.x & 63;
  int wv = threadIdx.x >> 6;
  const float4* wrow = reinterpret_cast<const float4*>(Wq + (size_t)o * ND) + lane * 4;
  float4 w0 = wrow[0], w1 = wrow[1], w2 = wrow[2], w3 = wrow[3];
#pragma unroll
  for (int bb = 0; bb < 8; ++bb) {
    int b = wv * 8 + bb;
    const float4* qr = reinterpret_cast<const float4*>(q + (size_t)b * ND) + lane * 4;
    float s = dot4(qr[0], w0) + dot4(qr[1], w1) + dot4(qr[2], w2) + dot4(qr[3], w3);
#pragma unroll
    for (int off = 32; off > 0; off >>= 1) s += __shfl_down(s, off, 64);
    if (lane == 0) qs[(size_t)b * ND + o] = s + bq[o];
  }
}

// ---------------------------------------------------------------------------
// K2: qt[b][n][i] = sum_d Wk[n*64+d][i] * qs[b][n*64+d]   grid=64 (n,ichunk)
// ---------------------------------------------------------------------------
__global__ __launch_bounds__(256) void qt_kernel(
    const float* __restrict__ Wk, const float* __restrict__ qs,
    float* __restrict__ qt) {
  int n = blockIdx.x >> 2;
  int ic = blockIdx.x & 3;
  int i = ic * 256 + threadIdx.x;
  __shared__ float s_qs[32][64];
  for (int t = threadIdx.x; t < 2048; t += 256) {
    int b = t >> 6, d = t & 63;
    s_qs[b][d] = qs[(size_t)b * ND + n * NDH + d];
  }
  __syncthreads();
  float acc[32];
#pragma unroll
  for (int b = 0; b < 32; ++b) acc[b] = 0.f;
  for (int d = 0; d < 64; ++d) {
    float w = Wk[((size_t)(n * NDH + d)) * ND + i];
#pragma unroll
    for (int b = 0; b < 32; ++b) acc[b] += w * s_qs[b][d];
  }
#pragma unroll
  for (int b = 0; b < 32; ++b)
    qt[((size_t)(b * NHH + n)) * ND + i] = acc[b];
}

// ---------------------------------------------------------------------------
// K2b: qb[b*16+n] = qs[b][n*64+:] . bk[n*64+:]    grid=2, block=256
// ---------------------------------------------------------------------------
__global__ __launch_bounds__(256) void qb_kernel(
    const float* __restrict__ qs, const float* __restrict__ bk,
    float* __restrict__ qb) {
  int t = blockIdx.x * 256 + threadIdx.x;
  if (t >= 512) return;
  int b = t >> 4, n = t & 15;
  float s = 0.f;
  for (int d = 0; d < 64; ++d)
    s += qs[(size_t)b * ND + n * NDH + d] * bk[n * NDH + d];
  qb[t] = s;
}

// ---------------------------------------------------------------------------
// K3: logits[n*32+b][l] = (qt[b][n] . k[b][l] + qb[b][n]) / 8   via bf16 MFMA
// ---------------------------------------------------------------------------
__global__ __launch_bounds__(256) void logits_kernel(
    const float* __restrict__ kin, const float* __restrict__ qt,
    const float* __restrict__ qb, float* __restrict__ attn) {
  int b = blockIdx.x >> 5;
  int lt = blockIdx.x & 31;
  int l0 = lt * 64;
  int tid = threadIdx.x;
  int lane = tid & 63, wv = tid >> 6;

  __shared__ __align__(16) char sA[16 * 1024 * 2];
  __shared__ __align__(16) char sB[64 * 256 * 2];

  {  // stage qt[b] -> sA (bf16, swizzled)
    int n = tid >> 4, c0 = (tid & 15) * 64;
    const float4* src =
        reinterpret_cast<const float4*>(qt + ((size_t)(b * NHH + n)) * ND + c0);
#pragma unroll
    for (int m = 0; m < 8; ++m) {
      float4 f0 = src[2 * m], f1 = src[2 * m + 1];
      bf16x8 v;
      v[0] = (bf16)f0.x; v[1] = (bf16)f0.y; v[2] = (bf16)f0.z; v[3] = (bf16)f0.w;
      v[4] = (bf16)f1.x; v[5] = (bf16)f1.y; v[6] = (bf16)f1.z; v[7] = (bf16)f1.w;
      int byte = ((n * 1024 + c0 + m * 8) * 2) ^ ((n & 7) << 4);
      *reinterpret_cast<bf16x8*>(sA + byte) = v;
    }
  }

  f32x4 acc = {0.f, 0.f, 0.f, 0.f};
  int rA = lane & 15;
  int kg = lane >> 4;

  for (int kc = 0; kc < ND; kc += 256) {
    __syncthreads();
    {  // stage k[b][l0..l0+63][kc..kc+255] -> sB
      int l = tid >> 2, cg = tid & 3;
      const float4* src = reinterpret_cast<const float4*>(
          kin + ((size_t)(b * NL + l0 + l)) * ND + kc + cg * 64);
#pragma unroll
      for (int m = 0; m < 8; ++m) {
        float4 f0 = src[2 * m], f1 = src[2 * m + 1];
        bf16x8 v;
        v[0] = (bf16)f0.x; v[1] = (bf16)f0.y; v[2] = (bf16)f0.z; v[3] = (bf16)f0.w;
        v[4] = (bf16)f1.x; v[5] = (bf16)f1.y; v[6] = (bf16)f1.z; v[7] = (bf16)f1.w;
        int byte = ((l * 256 + cg * 64 + m * 8) * 2) ^ ((l & 7) << 4);
        *reinterpret_cast<bf16x8*>(sB + byte) = v;
      }
    }
    __syncthreads();
    int lB = wv * 16 + rA;
#pragma unroll
    for (int kk = 0; kk < 8; ++kk) {
      int byteA = ((rA * 1024 + kc + kk * 32 + kg * 8) * 2) ^ ((rA & 7) << 4);
      bf16x8 a = *reinterpret_cast<const bf16x8*>(sA + byteA);
      int byteB = ((lB * 256 + kk * 32 + kg * 8) * 2) ^ ((lB & 7) << 4);
      bf16x8 bf = *reinterpret_cast<const bf16x8*>(sB + byteB);
      acc = __builtin_amdgcn_mfma_f32_16x16x32_bf16(a, bf, acc, 0, 0, 0);
    }
  }

  int c = lane & 15;
  int rb = (lane >> 4) * 4;
#pragma unroll
  for (int j = 0; j < 4; ++j) {
    int r = rb + j;  // head n
    float val = (acc[j] + qb[b * NHH + r]) * 0.125f;
    attn[((size_t)(r * NB + b)) * NL + l0 + wv * 16 + c] = val;
  }
}

// ---------------------------------------------------------------------------
// K4: in-place softmax over rows of 2048. grid=512, block=256
// ---------------------------------------------------------------------------
__global__ __launch_bounds__(256) void softmax_kernel(float* __restrict__ attn) {
  int row = blockIdx.x;
  float* p = attn + (size_t)row * NL;
  int tid = threadIdx.x;
  int lane = tid & 63, wv = tid >> 6;
  float v[8];
  float m = -1e30f;
#pragma unroll
  for (int j = 0; j < 8; ++j) {
    v[j] = p[tid + j * 256];
    m = fmaxf(m, v[j]);
  }
#pragma unroll
  for (int off = 32; off > 0; off >>= 1) m = fmaxf(m, __shfl_down(m, off, 64));
  __shared__ float sm[4], ss[4];
  if (lane == 0) sm[wv] = m;
  __syncthreads();
  float M = fmaxf(fmaxf(sm[0], sm[1]), fmaxf(sm[2], sm[3]));
  float s = 0.f;
#pragma unroll
  for (int j = 0; j < 8; ++j) {
    v[j] = __expf(v[j] - M);
    s += v[j];
  }
#pragma unroll
  for (int off = 32; off > 0; off >>= 1) s += __shfl_down(s, off, 64);
  if (lane == 0) ss[wv] = s;
  __syncthreads();
  float inv = 1.f / (ss[0] + ss[1] + ss[2] + ss[3]);
#pragma unroll
  for (int j = 0; j < 8; ++j) p[tid + j * 256] = v[j] * inv;
}

// ---------------------------------------------------------------------------
// K5: ctxp[ls][b][n][i-chunk] = sum_{l in slice ls} attn[n*32+b][l] * k[b][l][i]
// grid = 32 b x 4 ig(256 i) x 8 ls(256 l) = 1024 blocks, 256 threads.
// No atomics: each block writes its own partial slab (plain coalesced stores).
// ---------------------------------------------------------------------------
__global__ __launch_bounds__(256, 4) void ctx_kernel(
    const float* __restrict__ kin, const float* __restrict__ attn,
    float* __restrict__ ctxp) {
  int bx = blockIdx.x;
  int b  = bx >> 5;          // 0..31
  int ig = (bx >> 3) & 3;    // 0..3
  int ls = bx & 7;           // 0..7
  int tid = threadIdx.x, lane = tid & 63, wv = tid >> 6;

  __shared__ __align__(16) float sA[256][20];  // attn [l][n], rows 80B
  __shared__ __align__(16) float sC[16][256];  // combine buffer

  // stage attn slice: n = idx>>8, l = idx&255 (coalesced over l)
  for (int idx = tid; idx < 4096; idx += 256) {
    int n = idx >> 8, ll = idx & 255;
    sA[ll][n] = attn[((size_t)(n * NB + b)) * NL + ls * 256 + ll];
  }
  __syncthreads();

  f32x4 acc[16];
#pragma unroll
  for (int n = 0; n < 16; ++n) acc[n] = (f32x4){0.f, 0.f, 0.f, 0.f};

  const float* kp =
      kin + ((size_t)(b * NL + ls * 256 + wv * 64)) * ND + ig * 256 + lane * 4;
  int row0 = wv * 64;
#pragma unroll 2
  for (int l = 0; l < 64; ++l) {
    f32x4 kv = *reinterpret_cast<const f32x4*>(kp + (size_t)l * ND);
    const float* ar = sA[row0 + l];
    f32x4 aa[4];
    aa[0] = *reinterpret_cast<const f32x4*>(ar);
    aa[1] = *reinterpret_cast<const f32x4*>(ar + 4);
    aa[2] = *reinterpret_cast<const f32x4*>(ar + 8);
    aa[3] = *reinterpret_cast<const f32x4*>(ar + 12);
#pragma unroll
    for (int n = 0; n < 16; ++n) {
#pragma unroll
      for (int c = 0; c < 4; ++c)
        acc[n][c] += aa[n >> 2][n & 3] * kv[c];
    }
  }

  // combine 4 waves' partials in LDS (sequential adds)
  if (wv == 0) {
#pragma unroll
    for (int n = 0; n < 16; ++n)
      *reinterpret_cast<f32x4*>(&sC[n][lane * 4]) = acc[n];
  }
  __syncthreads();
#pragma unroll
  for (int w = 1; w < 4; ++w) {
    if (wv == w) {
#pragma unroll
      for (int n = 0; n < 16; ++n) {
        f32x4 cur = *reinterpret_cast<f32x4*>(&sC[n][lane * 4]);
        cur += acc[n];
        *reinterpret_cast<f32x4*>(&sC[n][lane * 4]) = cur;
      }
    }
    __syncthreads();
  }

  // plain store of block partial: ctxp[((ls*NB+b)*NHH+n)*ND + ig*256 + i]
  for (int idx = tid; idx < 4096; idx += 256) {
    int n = idx >> 8, i = idx & 255;
    ctxp[(((size_t)ls * NB + b) * NHH + n) * ND + ig * 256 + i] = sC[n][i];
  }
}

// ---------------------------------------------------------------------------
// K5b: ctx = sum_ls ctxp[ls]    512K floats, grid=512, block=256, float4 each
// ---------------------------------------------------------------------------
__global__ __launch_bounds__(256) void reduce_kernel(
    const float* __restrict__ ctxp, float* __restrict__ ctx) {
  size_t e4 = ((size_t)blockIdx.x * 256 + threadIdx.x) * 4;
  f32x4 s = *reinterpret_cast<const f32x4*>(ctxp + e4);
#pragma unroll
  for (int ls = 1; ls < 8; ++ls)
    s += *reinterpret_cast<const f32x4*>(ctxp + (size_t)ls * NB * NHH * ND + e4);
  *reinterpret_cast<f32x4*>(ctx + e4) = s;
}

// ---------------------------------------------------------------------------
// K6: out[b][o] = Wv[o] . ctx[b][o>>6] + bv[o]     grid=1024, block=256
// ---------------------------------------------------------------------------
__global__ __launch_bounds__(256) void out_kernel(
    const float* __restrict__ Wv, const float* __restrict__ bv,
    const float* __restrict__ ctx, float* __restrict__ out) {
  int o = blockIdx.x;
  int n = o >> 6;
  int lane = threadIdx.x & 63;
  int wv = threadIdx.x >> 6;
  const float4* wrow = reinterpret_cast<const float4*>(Wv + (size_t)o * ND) + lane * 4;
  float4 w0 = wrow[0], w1 = wrow[1], w2 = wrow[2], w3 = wrow[3];
#pragma unroll
  for (int bb = 0; bb < 8; ++bb) {
    int b = wv * 8 + bb;
    const float4* cr =
        reinterpret_cast<const float4*>(ctx + ((size_t)(b * NHH + n)) * ND) + lane * 4;
    float s = dot4(cr[0], w0) + dot4(cr[1], w1) + dot4(cr[2], w2) + dot4(cr[3], w3);
#pragma unroll
    for (int off = 32; off > 0; off >>= 1) s += __shfl_down(s, off, 64);
    if (lane == 0) out[(size_t)b * ND + o] = s + bv[o];
  }
}

// ---------------------------------------------------------------------------
extern "C" void kernel_launch(void* const* d_in, const int* in_sizes, int n_in,
                              void* d_out, int out_size, void* d_ws, size_t ws_size,
                              hipStream_t stream) {
  const float* q  = (const float*)d_in[0];
  const float* k  = (const float*)d_in[1];
  const float* Wq = (const float*)d_in[2];
  const float* bq = (const float*)d_in[3];
  const float* Wk = (const float*)d_in[4];
  const float* bk = (const float*)d_in[5];
  const float* Wv = (const float*)d_in[6];
  const float* bv = (const float*)d_in[7];

  float* out  = (float*)d_out;         // [32][1024]
  float* attn = out + NB * ND;         // [512][2048]  (n-major)

  // ws floats: qs 32768 | qt 524288 | qb 512 | ctx 524288 | ctxp 4194304
  float* ws   = (float*)d_ws;
  float* qs   = ws;
  float* qt   = ws + 32768;
  float* qb   = ws + 32768 + 524288;
  float* ctx  = ws + 32768 + 524288 + 512;
  float* ctxp = ctx + 524288;

  qs_kernel<<<1024, 256, 0, stream>>>(q, Wq, bq, qs);
  qt_kernel<<<64, 256, 0, stream>>>(Wk, qs, qt);
  qb_kernel<<<2, 256, 0, stream>>>(qs, bk, qb);
  logits_kernel<<<1024, 256, 0, stream>>>(k, qt, qb, attn);
  softmax_kernel<<<512, 256, 0, stream>>>(attn);
  ctx_kernel<<<1024, 256, 0, stream>>>(k, attn, ctxp);
  reduce_kernel<<<512, 256, 0, stream>>>(ctxp, ctx);
  out_kernel<<<1024, 256, 0, stream>>>(Wv, bv, ctx, out);
}